// Round 1
// baseline (965.691 us; speedup 1.0000x reference)
//
#include <hip/hip_runtime.h>

#define CIN 128
#define CO  64

__device__ __forceinline__ float lrelu(float x, float s) { return x > 0.f ? x : x * s; }

// K1: xl = x @ W^T + b ; s_i/s_j per-node attention scores, fused.
// Each lane holds one W row (128 VGPRs); x rows are wave-uniform -> scalar loads.
__global__ __launch_bounds__(256, 2) void k_gemm_scores(
    const float* __restrict__ x, const float* __restrict__ W,
    const float* __restrict__ bvec, const float* __restrict__ emb,
    const float* __restrict__ ai, const float* __restrict__ aj,
    const float* __restrict__ aei, const float* __restrict__ aej,
    float* __restrict__ xl, float* __restrict__ s_i, float* __restrict__ s_j, int N)
{
    __shared__ float wlds[CO * (CIN + 1)];          // +1 pad: bank (c+k)%32, 2-way = free
    for (int i = threadIdx.x; i < CO * CIN; i += 256) {
        int c = i >> 7, k = i & (CIN - 1);
        wlds[c * (CIN + 1) + k] = W[i];
    }
    __syncthreads();
    const int lane = threadIdx.x & 63;
    float wreg[CIN];
#pragma unroll
    for (int k = 0; k < CIN; ++k) wreg[k] = wlds[lane * (CIN + 1) + k];
    const float bi  = bvec[lane];
    const float vai = ai[lane], vaj = aj[lane], vaei = aei[lane], vaej = aej[lane];
    int wv = __builtin_amdgcn_readfirstlane((int)(threadIdx.x >> 6));
    int gw = blockIdx.x * 4 + wv;
    int nwaves = gridDim.x * 4;
    for (int n = gw; n < N; n += nwaves) {
        const float4* xr = (const float4*)(x + (size_t)n * CIN);  // uniform addr -> s_load
        float acc = bi;
#pragma unroll
        for (int k4 = 0; k4 < CIN / 4; ++k4) {
            float4 xv = xr[k4];
            acc = fmaf(xv.x, wreg[4 * k4 + 0], acc);
            acc = fmaf(xv.y, wreg[4 * k4 + 1], acc);
            acc = fmaf(xv.z, wreg[4 * k4 + 2], acc);
            acc = fmaf(xv.w, wreg[4 * k4 + 3], acc);
        }
        xl[(size_t)n * CO + lane] = acc;
        float e  = emb[(size_t)n * CO + lane];
        float di = acc * vai + e * vaei;
        float dj = acc * vaj + e * vaej;
#pragma unroll
        for (int off = 32; off; off >>= 1) {
            di += __shfl_xor(di, off);
            dj += __shfl_xor(dj, off);
        }
        if (lane == 0) { s_i[n] = di; s_j[n] = dj; }
    }
}

// K2: in-degree histogram over real edges
__global__ void k_hist(const int* __restrict__ dst, int E, int* __restrict__ count)
{
    int i = blockIdx.x * 256 + threadIdx.x;
    if (i < E) atomicAdd(&count[dst[i]], 1);
}

// K3a: per-block inclusive scan of (count[i]+1)  (+1 = implicit self-loop)
__global__ __launch_bounds__(1024) void k_scan1(const int* __restrict__ count, int N,
                                                int* __restrict__ row, int* __restrict__ bsum)
{
    __shared__ int s[1024];
    int t = threadIdx.x;
    int i = blockIdx.x * 1024 + t;
    int v = (i < N) ? count[i] + 1 : 0;
    s[t] = v;
    __syncthreads();
    for (int off = 1; off < 1024; off <<= 1) {
        int y = (t >= off) ? s[t - off] : 0;
        __syncthreads();
        s[t] += y;
        __syncthreads();
    }
    if (i < N) row[i + 1] = s[t];
    if (t == 1023) bsum[blockIdx.x] = s[t];
}

// K3b: exclusive scan of block sums (NB <= 128)
__global__ __launch_bounds__(128) void k_scan2(const int* __restrict__ bsum, int NB,
                                               int* __restrict__ boff)
{
    __shared__ int s[128];
    int t = threadIdx.x;
    int v = (t < NB) ? bsum[t] : 0;
    s[t] = v;
    __syncthreads();
    for (int off = 1; off < 128; off <<= 1) {
        int y = (t >= off) ? s[t - off] : 0;
        __syncthreads();
        s[t] += y;
        __syncthreads();
    }
    boff[t] = s[t] - v;
}

// K3c: add block offsets -> row_start (exclusive CSR offsets, slots include self-loop)
__global__ __launch_bounds__(1024) void k_scan3(int N, int* __restrict__ row,
                                                const int* __restrict__ boff)
{
    int t = threadIdx.x;
    int i = blockIdx.x * 1024 + t;
    if (i == 0) row[0] = 0;
    if (i < N) row[i + 1] += boff[blockIdx.x];
}

// K4: scatter src into CSR order (self-loop slot at segment end stays implicit)
__global__ void k_fill(const int* __restrict__ src, const int* __restrict__ dst, int E,
                       const int* __restrict__ row, int* __restrict__ cursor,
                       int* __restrict__ ssort)
{
    int i = blockIdx.x * 256 + threadIdx.x;
    if (i < E) {
        int d = dst[i];
        int pos = row[d] + atomicAdd(&cursor[d], 1);
        ssort[pos] = src[i];
    }
}

// K5: per-node online softmax + aggregation (wave per node, lane = channel). No atomics
// on agg; writes pre-BN out, per-node amax/denom, and contention-spread BN partials.
__global__ __launch_bounds__(256) void k_agg(
    const float* __restrict__ xl, const float* __restrict__ s_i, const float* __restrict__ s_j,
    const int* __restrict__ row, const int* __restrict__ ssort,
    const float* __restrict__ bias, int N,
    float* __restrict__ outp, float* __restrict__ amax, float* __restrict__ denom,
    float* __restrict__ spread)
{
    int lane = threadIdx.x & 63;
    int wv   = threadIdx.x >> 6;
    int n    = blockIdx.x * 4 + wv;
    if (n >= N) return;
    int r0 = row[n], r1 = row[n + 1];
    int cntE = r1 - r0 - 1;                       // real in-edges (last slot = self)
    float si_n  = s_i[n];
    float aself = lrelu(si_n + s_j[n], 0.2f);
    float m = aself;
    for (int k = lane; k < cntE; k += 64) {
        int s = ssort[r0 + k];
        m = fmaxf(m, lrelu(si_n + s_j[s], 0.2f));
    }
#pragma unroll
    for (int off = 32; off; off >>= 1) m = fmaxf(m, __shfl_xor(m, off));
    float eself = __expf(aself - m);
    float den = eself;
    float acc = eself * xl[(size_t)n * CO + lane];
    for (int k = 0; k < cntE; ++k) {
        int s = ssort[r0 + k];                    // wave-uniform -> s_load broadcast
        float e = __expf(lrelu(si_n + s_j[s], 0.2f) - m);
        den += e;
        acc += e * xl[(size_t)s * CO + lane];     // coalesced 256B row gather
    }
    float val = acc / den + bias[lane];
    outp[(size_t)n * CO + lane] = val;
    if (lane == 0) { amax[n] = m; denom[n] = den; }
    int slot = (blockIdx.x * 4 + wv) & 255;
    atomicAdd(&spread[slot * 128 + lane],      val);
    atomicAdd(&spread[slot * 128 + 64 + lane], val * val);
}

// K6: att_weight in ORIGINAL edge order (E real edges then N self-loops)
__global__ void k_att(const int* __restrict__ src, const int* __restrict__ dst, int E, int N,
                      const float* __restrict__ s_i, const float* __restrict__ s_j,
                      const float* __restrict__ amax, const float* __restrict__ denom,
                      float* __restrict__ att)
{
    int i = blockIdx.x * 256 + threadIdx.x;
    int tot = E + N;
    if (i >= tot) return;
    int s, d;
    if (i < E) { s = src[i]; d = dst[i]; } else { s = d = i - E; }
    float a = lrelu(s_i[d] + s_j[s], 0.2f);
    att[i] = __expf(a - amax[d]) / denom[d];
}

// K7: reduce BN partials -> per-channel scale/shift
__global__ __launch_bounds__(1024) void k_bnstats(const float* __restrict__ spread, int N,
    const float* __restrict__ gamma, const float* __restrict__ beta,
    float* __restrict__ scale, float* __restrict__ shift)
{
    __shared__ float red[8][128];
    __shared__ float tot[128];
    int c = threadIdx.x & 127;
    int p = threadIdx.x >> 7;
    float a = 0.f;
    for (int s = p; s < 256; s += 8) a += spread[s * 128 + c];
    red[p][c] = a;
    __syncthreads();
    if (threadIdx.x < 128) {
        float t = 0.f;
        for (int q = 0; q < 8; ++q) t += red[q][c];
        tot[c] = t;
    }
    __syncthreads();
    if (threadIdx.x < 64) {
        float inv = 1.f / (float)N;
        float mu  = tot[threadIdx.x] * inv;
        float msq = tot[64 + threadIdx.x] * inv;
        float var = msq - mu * mu;
        float sc  = gamma[threadIdx.x] * rsqrtf(var + 1e-5f);
        scale[threadIdx.x] = sc;
        shift[threadIdx.x] = beta[threadIdx.x] - mu * sc;
    }
}

// K8: in-place BN + leaky(0.01) epilogue on d_out node block, float4-vectorized
__global__ void k_bnapply(float* __restrict__ outp, int N,
                          const float* __restrict__ scale, const float* __restrict__ shift)
{
    int i = blockIdx.x * 256 + threadIdx.x;     // float4 index
    int tot = N * CO / 4;
    if (i >= tot) return;
    float4 v = ((float4*)outp)[i];
    int c0 = (i * 4) & (CO - 1);
    v.x = lrelu(fmaf(scale[c0 + 0], v.x, shift[c0 + 0]), 0.01f);
    v.y = lrelu(fmaf(scale[c0 + 1], v.y, shift[c0 + 1]), 0.01f);
    v.z = lrelu(fmaf(scale[c0 + 2], v.z, shift[c0 + 2]), 0.01f);
    v.w = lrelu(fmaf(scale[c0 + 3], v.w, shift[c0 + 3]), 0.01f);
    ((float4*)outp)[i] = v;
}

extern "C" void kernel_launch(void* const* d_in, const int* in_sizes, int n_in,
                              void* d_out, int out_size, void* d_ws, size_t ws_size,
                              hipStream_t stream)
{
    const float* x    = (const float*)d_in[0];
    const int*   ei   = (const int*)  d_in[1];
    const float* emb  = (const float*)d_in[2];
    const float* W    = (const float*)d_in[3];
    const float* lb   = (const float*)d_in[4];
    const float* ai   = (const float*)d_in[5];
    const float* aj   = (const float*)d_in[6];
    const float* aei  = (const float*)d_in[7];
    const float* aej  = (const float*)d_in[8];
    const float* bias = (const float*)d_in[9];
    const float* gam  = (const float*)d_in[10];
    const float* bet  = (const float*)d_in[11];

    int N = in_sizes[0] / CIN;
    int E = in_sizes[1] / 2;
    const int* srcv = ei;
    const int* dstv = ei + E;

    float* ws = (float*)d_ws;
    size_t o = 0;
    float* xl    = ws + o; o += (size_t)N * CO;
    float* s_i   = ws + o; o += N;
    float* s_j   = ws + o; o += N;
    float* amax  = ws + o; o += N;
    float* denom = ws + o; o += N;
    int*   row   = (int*)(ws + o); o += (size_t)N + 1;
    int*   bsum  = (int*)(ws + o); o += 128;
    int*   boff  = (int*)(ws + o); o += 128;
    size_t zoff  = o;                               // ---- zeroed region start ----
    int*   count = (int*)(ws + o); o += N;
    int*   cursor= (int*)(ws + o); o += N;
    float* spread= ws + o;         o += 256 * 128;
    size_t zbytes = (o - zoff) * sizeof(float);     // ---- zeroed region end ----
    float* scale = ws + o; o += CO;
    float* shift = ws + o; o += CO;
    int*   ssort = (int*)(ws + o); o += E;

    float* out_nodes = (float*)d_out;
    float* out_att   = out_nodes + (size_t)N * CO;

    hipMemsetAsync((void*)count, 0, zbytes, stream);

    k_gemm_scores<<<1024, 256, 0, stream>>>(x, W, lb, emb, ai, aj, aei, aej, xl, s_i, s_j, N);
    k_hist<<<(E + 255) / 256, 256, 0, stream>>>(dstv, E, count);
    int NB = (N + 1023) / 1024;
    k_scan1<<<NB, 1024, 0, stream>>>(count, N, row, bsum);
    k_scan2<<<1, 128, 0, stream>>>(bsum, NB, boff);
    k_scan3<<<NB, 1024, 0, stream>>>(N, row, boff);
    k_fill<<<(E + 255) / 256, 256, 0, stream>>>(srcv, dstv, E, row, cursor, ssort);
    k_agg<<<(N + 3) / 4, 256, 0, stream>>>(xl, s_i, s_j, row, ssort, bias, N,
                                           out_nodes, amax, denom, spread);
    k_att<<<(E + N + 255) / 256, 256, 0, stream>>>(srcv, dstv, E, N, s_i, s_j, amax, denom, out_att);
    k_bnstats<<<1, 1024, 0, stream>>>(spread, N, gam, bet, scale, shift);
    k_bnapply<<<((N * CO / 4) + 255) / 256, 256, 0, stream>>>(out_nodes, N, scale, shift);
}

// Round 2
// 746.447 us; speedup vs baseline: 1.2937x; 1.2937x over previous
//
#include <hip/hip_runtime.h>
#include <hip/hip_bf16.h>

#define CIN 128
#define CO  64

__device__ __forceinline__ float lrelu(float x, float s) { return x > 0.f ? x : x * s; }

// K1: xl = x @ W^T + b (stored bf16); s_i/s_j per-node attention scores, fused.
// Each lane holds one W row (128 VGPRs); x rows are wave-uniform -> scalar loads.
__global__ __launch_bounds__(256, 2) void k_gemm_scores(
    const float* __restrict__ x, const float* __restrict__ W,
    const float* __restrict__ bvec, const float* __restrict__ emb,
    const float* __restrict__ ai, const float* __restrict__ aj,
    const float* __restrict__ aei, const float* __restrict__ aej,
    __hip_bfloat16* __restrict__ xlb, float* __restrict__ s_i, float* __restrict__ s_j, int N)
{
    __shared__ float wlds[CO * (CIN + 1)];          // +1 pad: bank (c+k)%32, 2-way = free
    for (int i = threadIdx.x; i < CO * CIN; i += 256) {
        int c = i >> 7, k = i & (CIN - 1);
        wlds[c * (CIN + 1) + k] = W[i];
    }
    __syncthreads();
    const int lane = threadIdx.x & 63;
    float wreg[CIN];
#pragma unroll
    for (int k = 0; k < CIN; ++k) wreg[k] = wlds[lane * (CIN + 1) + k];
    const float bi  = bvec[lane];
    const float vai = ai[lane], vaj = aj[lane], vaei = aei[lane], vaej = aej[lane];
    int wv = __builtin_amdgcn_readfirstlane((int)(threadIdx.x >> 6));
    int gw = blockIdx.x * 4 + wv;
    int nwaves = gridDim.x * 4;
    for (int n = gw; n < N; n += nwaves) {
        const float4* xr = (const float4*)(x + (size_t)n * CIN);  // uniform addr -> s_load
        float acc = bi;
#pragma unroll
        for (int k4 = 0; k4 < CIN / 4; ++k4) {
            float4 xv = xr[k4];
            acc = fmaf(xv.x, wreg[4 * k4 + 0], acc);
            acc = fmaf(xv.y, wreg[4 * k4 + 1], acc);
            acc = fmaf(xv.z, wreg[4 * k4 + 2], acc);
            acc = fmaf(xv.w, wreg[4 * k4 + 3], acc);
        }
        xlb[(size_t)n * CO + lane] = __float2bfloat16(acc);
        float e  = emb[(size_t)n * CO + lane];
        float di = acc * vai + e * vaei;
        float dj = acc * vaj + e * vaej;
#pragma unroll
        for (int off = 32; off; off >>= 1) {
            di += __shfl_xor(di, off);
            dj += __shfl_xor(dj, off);
        }
        if (lane == 0) { s_i[n] = di; s_j[n] = dj; }
    }
}

// K2: in-degree histogram over real edges
__global__ void k_hist(const int* __restrict__ dst, int E, int* __restrict__ count)
{
    int i = blockIdx.x * 256 + threadIdx.x;
    if (i < E) atomicAdd(&count[dst[i]], 1);
}

// K3a: per-block inclusive scan of (count[i]+1)  (+1 = implicit self-loop)
__global__ __launch_bounds__(1024) void k_scan1(const int* __restrict__ count, int N,
                                                int* __restrict__ row, int* __restrict__ bsum)
{
    __shared__ int s[1024];
    int t = threadIdx.x;
    int i = blockIdx.x * 1024 + t;
    int v = (i < N) ? count[i] + 1 : 0;
    s[t] = v;
    __syncthreads();
    for (int off = 1; off < 1024; off <<= 1) {
        int y = (t >= off) ? s[t - off] : 0;
        __syncthreads();
        s[t] += y;
        __syncthreads();
    }
    if (i < N) row[i + 1] = s[t];
    if (t == 1023) bsum[blockIdx.x] = s[t];
}

// K3b: exclusive scan of block sums (NB <= 128)
__global__ __launch_bounds__(128) void k_scan2(const int* __restrict__ bsum, int NB,
                                               int* __restrict__ boff)
{
    __shared__ int s[128];
    int t = threadIdx.x;
    int v = (t < NB) ? bsum[t] : 0;
    s[t] = v;
    __syncthreads();
    for (int off = 1; off < 128; off <<= 1) {
        int y = (t >= off) ? s[t - off] : 0;
        __syncthreads();
        s[t] += y;
        __syncthreads();
    }
    boff[t] = s[t] - v;
}

// K3c: add block offsets -> row (exclusive CSR offsets, slots include self-loop)
__global__ __launch_bounds__(1024) void k_scan3(int N, int* __restrict__ row,
                                                const int* __restrict__ boff)
{
    int t = threadIdx.x;
    int i = blockIdx.x * 1024 + t;
    if (i == 0) row[0] = 0;
    if (i < N) row[i + 1] += boff[blockIdx.x];
}

// K4: scatter src into CSR order (self-loop slot at segment end stays implicit)
__global__ void k_fill(const int* __restrict__ src, const int* __restrict__ dst, int E,
                       const int* __restrict__ row, int* __restrict__ cursor,
                       int* __restrict__ ssort)
{
    int i = blockIdx.x * 256 + threadIdx.x;
    if (i < E) {
        int d = dst[i];
        int pos = row[d] + atomicAdd(&cursor[d], 1);
        ssort[pos] = src[i];
    }
}

// K5: per-node softmax + aggregation, NO max pre-pass (exp(a)/sum(exp(a)) is exactly
// the softmax; scores are O(10) so no fp32 overflow). Wave per node, lane = channel.
// Unroll-8 batches break the load latency chain (MLP=8 on s_j and xl gathers).
__global__ __launch_bounds__(256) void k_agg(
    const __hip_bfloat16* __restrict__ xlb,
    const float* __restrict__ s_i, const float* __restrict__ s_j,
    const int* __restrict__ row, const int* __restrict__ ssort,
    const float* __restrict__ bias, int N,
    float* __restrict__ outp, float2* __restrict__ pd,
    float* __restrict__ spread)
{
    int lane = threadIdx.x & 63;
    int wv   = threadIdx.x >> 6;
    int n    = blockIdx.x * 4 + wv;
    if (n >= N) return;
    int r0 = row[n], r1 = row[n + 1];
    int cntE = r1 - r0 - 1;                       // real in-edges (last slot = self)
    float si_n  = s_i[n];
    float eself = __expf(lrelu(si_n + s_j[n], 0.2f));
    float den = eself;
    float acc = eself * __bfloat162float(xlb[(size_t)n * CO + lane]);
    int k = 0;
    int cnt8 = cntE & ~7;
    for (; k < cnt8; k += 8) {
        const int* sp = ssort + r0 + k;
        int sv[8];
#pragma unroll
        for (int u = 0; u < 8; ++u) sv[u] = sp[u];
        float sjv[8];
#pragma unroll
        for (int u = 0; u < 8; ++u) sjv[u] = s_j[sv[u]];        // 8 gathers in flight
        float xv[8];
#pragma unroll
        for (int u = 0; u < 8; ++u)
            xv[u] = __bfloat162float(xlb[(size_t)sv[u] * CO + lane]); // 8 row gathers in flight
        float ev[8];
#pragma unroll
        for (int u = 0; u < 8; ++u) ev[u] = __expf(lrelu(si_n + sjv[u], 0.2f));
#pragma unroll
        for (int u = 0; u < 8; ++u) { den += ev[u]; acc = fmaf(ev[u], xv[u], acc); }
    }
    for (; k < cntE; ++k) {
        int s = ssort[r0 + k];
        float e = __expf(lrelu(si_n + s_j[s], 0.2f));
        den += e;
        acc = fmaf(e, __bfloat162float(xlb[(size_t)s * CO + lane]), acc);
    }
    float inv = 1.0f / den;
    float val = acc * inv + bias[lane];
    outp[(size_t)n * CO + lane] = val;
    if (lane == 0) pd[n] = make_float2(si_n, inv);
    int slot = (blockIdx.x * 4 + wv) & 255;
    atomicAdd(&spread[slot * 128 + lane],      val);
    atomicAdd(&spread[slot * 128 + 64 + lane], val * val);
}

// K6: att_weight in ORIGINAL edge order (E real edges then N self-loops).
// 2 gathers/edge: pd[d]=(s_i,1/denom) 8B + s_j[s] 4B.
__global__ void k_att(const int* __restrict__ src, const int* __restrict__ dst, int E, int N,
                      const float2* __restrict__ pd, const float* __restrict__ s_j,
                      float* __restrict__ att)
{
    int i = blockIdx.x * 256 + threadIdx.x;
    int tot = E + N;
    if (i >= tot) return;
    int s, d;
    if (i < E) { s = src[i]; d = dst[i]; } else { s = d = i - E; }
    float2 p = pd[d];
    float a = lrelu(p.x + s_j[s], 0.2f);
    att[i] = __expf(a) * p.y;
}

// K7: reduce BN partials -> per-channel scale/shift
__global__ __launch_bounds__(1024) void k_bnstats(const float* __restrict__ spread, int N,
    const float* __restrict__ gamma, const float* __restrict__ beta,
    float* __restrict__ scale, float* __restrict__ shift)
{
    __shared__ float red[8][128];
    __shared__ float tot[128];
    int c = threadIdx.x & 127;
    int p = threadIdx.x >> 7;
    float a = 0.f;
    for (int s = p; s < 256; s += 8) a += spread[s * 128 + c];
    red[p][c] = a;
    __syncthreads();
    if (threadIdx.x < 128) {
        float t = 0.f;
        for (int q = 0; q < 8; ++q) t += red[q][c];
        tot[c] = t;
    }
    __syncthreads();
    if (threadIdx.x < 64) {
        float inv = 1.f / (float)N;
        float mu  = tot[threadIdx.x] * inv;
        float msq = tot[64 + threadIdx.x] * inv;
        float var = msq - mu * mu;
        float sc  = gamma[threadIdx.x] * rsqrtf(var + 1e-5f);
        scale[threadIdx.x] = sc;
        shift[threadIdx.x] = beta[threadIdx.x] - mu * sc;
    }
}

// K8: in-place BN + leaky(0.01) epilogue on d_out node block, float4-vectorized
__global__ void k_bnapply(float* __restrict__ outp, int N,
                          const float* __restrict__ scale, const float* __restrict__ shift)
{
    int i = blockIdx.x * 256 + threadIdx.x;     // float4 index
    int tot = N * CO / 4;
    if (i >= tot) return;
    float4 v = ((float4*)outp)[i];
    int c0 = (i * 4) & (CO - 1);
    v.x = lrelu(fmaf(scale[c0 + 0], v.x, shift[c0 + 0]), 0.01f);
    v.y = lrelu(fmaf(scale[c0 + 1], v.y, shift[c0 + 1]), 0.01f);
    v.z = lrelu(fmaf(scale[c0 + 2], v.z, shift[c0 + 2]), 0.01f);
    v.w = lrelu(fmaf(scale[c0 + 3], v.w, shift[c0 + 3]), 0.01f);
    ((float4*)outp)[i] = v;
}

extern "C" void kernel_launch(void* const* d_in, const int* in_sizes, int n_in,
                              void* d_out, int out_size, void* d_ws, size_t ws_size,
                              hipStream_t stream)
{
    const float* x    = (const float*)d_in[0];
    const int*   ei   = (const int*)  d_in[1];
    const float* emb  = (const float*)d_in[2];
    const float* W    = (const float*)d_in[3];
    const float* lb   = (const float*)d_in[4];
    const float* ai   = (const float*)d_in[5];
    const float* aj   = (const float*)d_in[6];
    const float* aei  = (const float*)d_in[7];
    const float* aej  = (const float*)d_in[8];
    const float* bias = (const float*)d_in[9];
    const float* gam  = (const float*)d_in[10];
    const float* bet  = (const float*)d_in[11];

    int N = in_sizes[0] / CIN;
    int E = in_sizes[1] / 2;
    const int* srcv = ei;
    const int* dstv = ei + E;

    float* ws = (float*)d_ws;
    size_t o = 0;
    __hip_bfloat16* xlb = (__hip_bfloat16*)(ws + o); o += (size_t)N * CO / 2;
    float* s_i   = ws + o; o += N;
    float* s_j   = ws + o; o += N;
    float2* pd   = (float2*)(ws + o); o += 2 * (size_t)N;
    int*   row   = (int*)(ws + o); o += (size_t)N + 1;
    o += (o & 1);                                   // even-align
    int*   bsum  = (int*)(ws + o); o += 128;
    int*   boff  = (int*)(ws + o); o += 128;
    size_t zoff  = o;                               // ---- zeroed region start ----
    int*   count = (int*)(ws + o); o += N;
    int*   cursor= (int*)(ws + o); o += N;
    float* spread= ws + o;         o += 256 * 128;
    size_t zbytes = (o - zoff) * sizeof(float);     // ---- zeroed region end ----
    float* scale = ws + o; o += CO;
    float* shift = ws + o; o += CO;
    int*   ssort = (int*)(ws + o); o += E;

    float* out_nodes = (float*)d_out;
    float* out_att   = out_nodes + (size_t)N * CO;

    hipMemsetAsync((void*)count, 0, zbytes, stream);

    k_gemm_scores<<<1024, 256, 0, stream>>>(x, W, lb, emb, ai, aj, aei, aej, xlb, s_i, s_j, N);
    k_hist<<<(E + 255) / 256, 256, 0, stream>>>(dstv, E, count);
    int NB = (N + 1023) / 1024;
    k_scan1<<<NB, 1024, 0, stream>>>(count, N, row, bsum);
    k_scan2<<<1, 128, 0, stream>>>(bsum, NB, boff);
    k_scan3<<<NB, 1024, 0, stream>>>(N, row, boff);
    k_fill<<<(E + 255) / 256, 256, 0, stream>>>(srcv, dstv, E, row, cursor, ssort);
    k_agg<<<(N + 3) / 4, 256, 0, stream>>>(xlb, s_i, s_j, row, ssort, bias, N,
                                           out_nodes, pd, spread);
    k_att<<<(E + N + 255) / 256, 256, 0, stream>>>(srcv, dstv, E, N, pd, s_j, out_att);
    k_bnstats<<<1, 1024, 0, stream>>>(spread, N, gam, bet, scale, shift);
    k_bnapply<<<((N * CO / 4) + 255) / 256, 256, 0, stream>>>(out_nodes, N, scale, shift);
}

// Round 3
// 616.609 us; speedup vs baseline: 1.5661x; 1.2106x over previous
//
#include <hip/hip_runtime.h>
#include <hip/hip_bf16.h>

#define CIN 128
#define CO  64

typedef __attribute__((ext_vector_type(8))) short shortx8;
typedef __attribute__((ext_vector_type(4))) float floatx4;

__device__ __forceinline__ float lrelu(float x, float s) { return x > 0.f ? x : x * s; }

__device__ __forceinline__ short f2bs(float f) {
    union { __hip_bfloat16 h; short s; } u;
    u.h = __float2bfloat16(f);
    return u.s;
}

__device__ __forceinline__ shortx8 pack8(const float4& a, const float4& b) {
    shortx8 r;
    r[0] = f2bs(a.x); r[1] = f2bs(a.y); r[2] = f2bs(a.z); r[3] = f2bs(a.w);
    r[4] = f2bs(b.x); r[5] = f2bs(b.y); r[6] = f2bs(b.z); r[7] = f2bs(b.w);
    return r;
}

// K0: emb-part of attention scores: sie[n] = emb[n]·att_em_i, sje[n] = emb[n]·att_em_j.
// Wave handles 4 nodes/iter; lane = (node_off, float4 slot); coalesced 1KB loads.
__global__ __launch_bounds__(256) void k_escore(
    const float* __restrict__ emb, const float* __restrict__ aei, const float* __restrict__ aej,
    float* __restrict__ sie, float* __restrict__ sje, int N)
{
    int lane = threadIdx.x & 63;
    int slot = lane & 15, grp = lane >> 4;
    float4 vi = ((const float4*)aei)[slot];
    float4 vj = ((const float4*)aej)[slot];
    int w = blockIdx.x * 4 + (threadIdx.x >> 6);
    int nwaves = gridDim.x * 4;
    int groups = (N + 3) >> 2;
    for (int g = w; g < groups; g += nwaves) {
        int n = g * 4 + grp;
        float pi = 0.f, pj = 0.f;
        if (n < N) {
            float4 e = ((const float4*)(emb + (size_t)n * CO))[slot];
            pi = e.x * vi.x + e.y * vi.y + e.z * vi.z + e.w * vi.w;
            pj = e.x * vj.x + e.y * vj.y + e.z * vj.z + e.w * vj.w;
        }
#pragma unroll
        for (int off = 1; off < 16; off <<= 1) {
            pi += __shfl_xor(pi, off);
            pj += __shfl_xor(pj, off);
        }
        if (slot == 0 && n < N) { sie[n] = pi; sje[n] = pj; }
    }
}

// K1: MFMA GEMM xl = x@W^T + b (16x16x32 bf16). Wave holds ALL of W as 16 B-frags
// (64 VGPR), grid-strides over 16-node tiles. Epilogue fuses bias + s_i/s_j dots
// (quad shfl-reduce) + bf16 write via per-wave LDS transpose (stride 72 vs bank align).
// A-frag: A[m=lane&15][k=quad*8+j]; B-frag: B[k=quad*8+j][n=lane&15]; C/D: col=lane&15,
// row=quad*4+reg (per verified gfx950 layouts).
__global__ __launch_bounds__(256) void k_gemm(
    const float* __restrict__ x, const float* __restrict__ W,
    const float* __restrict__ lb, const float* __restrict__ ai, const float* __restrict__ aj,
    const float* __restrict__ sie, const float* __restrict__ sje,
    __hip_bfloat16* __restrict__ xlb, float* __restrict__ s_i, float* __restrict__ s_j, int N)
{
    __shared__ __hip_bfloat16 tile[4][16 * 72];
    const int lane = threadIdx.x & 63;
    const int wv   = threadIdx.x >> 6;
    const int col0 = lane & 15;
    const int quad = lane >> 4;

    shortx8 wf[4][4];                            // [channel-group][k-step]
#pragma unroll
    for (int cg = 0; cg < 4; ++cg)
#pragma unroll
        for (int ks = 0; ks < 4; ++ks) {
            const float* wp = W + (cg * 16 + col0) * CIN + ks * 32 + quad * 8;
            float4 w0 = *(const float4*)wp;
            float4 w1 = *(const float4*)(wp + 4);
            wf[cg][ks] = pack8(w0, w1);
        }
    float biasv[4], aiv[4], ajv[4];
#pragma unroll
    for (int cg = 0; cg < 4; ++cg) {
        biasv[cg] = lb[cg * 16 + col0];
        aiv[cg]   = ai[cg * 16 + col0];
        ajv[cg]   = aj[cg * 16 + col0];
    }

    int tiles = (N + 15) >> 4;
    for (int t = blockIdx.x * 4 + wv; t < tiles; t += gridDim.x * 4) {
        int n0 = t * 16;
        int arow = n0 + col0; if (arow > N - 1) arow = N - 1;
        const float* xp = x + (size_t)arow * CIN + quad * 8;
        float4 a0[4], a1[4];
#pragma unroll
        for (int ks = 0; ks < 4; ++ks) {         // 8 independent loads in flight
            a0[ks] = *(const float4*)(xp + ks * 32);
            a1[ks] = *(const float4*)(xp + ks * 32 + 4);
        }
        floatx4 z = {0.f, 0.f, 0.f, 0.f};
        floatx4 acc[4] = {z, z, z, z};
#pragma unroll
        for (int ks = 0; ks < 4; ++ks) {
            shortx8 af = pack8(a0[ks], a1[ks]);
#pragma unroll
            for (int cg = 0; cg < 4; ++cg)
                acc[cg] = __builtin_amdgcn_mfma_f32_16x16x32_bf16(af, wf[cg][ks], acc[cg], 0, 0, 0);
        }
        float pi[4] = {0, 0, 0, 0}, pj[4] = {0, 0, 0, 0};
        __hip_bfloat16* tp = tile[wv];
#pragma unroll
        for (int cg = 0; cg < 4; ++cg)
#pragma unroll
            for (int r = 0; r < 4; ++r) {
                float v = acc[cg][r] + biasv[cg];
                pi[r] = fmaf(v, aiv[cg], pi[r]);
                pj[r] = fmaf(v, ajv[cg], pj[r]);
                tp[(quad * 4 + r) * 72 + cg * 16 + col0] = __float2bfloat16(v);
            }
        __asm__ __volatile__("s_waitcnt lgkmcnt(0)" ::: "memory");  // wave-sync LDS transpose
        int rr = lane >> 2, hh = lane & 3;       // lane covers 32B of one row
        int orow = n0 + rr;
        if (orow < N) {
            const float4* sp = (const float4*)(tp + rr * 72 + hh * 16);
            float4 v0 = sp[0], v1 = sp[1];
            float4* gp = (float4*)(xlb + (size_t)orow * CO + hh * 16);
            gp[0] = v0; gp[1] = v1;
        }
#pragma unroll
        for (int r = 0; r < 4; ++r)
#pragma unroll
            for (int off = 1; off < 16; off <<= 1) {
                pi[r] += __shfl_xor(pi[r], off);
                pj[r] += __shfl_xor(pj[r], off);
            }
        if (col0 == 0) {
#pragma unroll
            for (int r = 0; r < 4; ++r) {
                int n = n0 + quad * 4 + r;
                if (n < N) {
                    s_i[n] = sie[n] + pi[r];
                    s_j[n] = sje[n] + pj[r];
                }
            }
        }
    }
}

// K2: in-degree histogram over real edges
__global__ void k_hist(const int* __restrict__ dst, int E, int* __restrict__ count)
{
    int i = blockIdx.x * 256 + threadIdx.x;
    if (i < E) atomicAdd(&count[dst[i]], 1);
}

// K3a: per-block inclusive scan of (count[i]+1)  (+1 = implicit self-loop)
__global__ __launch_bounds__(1024) void k_scan1(const int* __restrict__ count, int N,
                                                int* __restrict__ row, int* __restrict__ bsum)
{
    __shared__ int s[1024];
    int t = threadIdx.x;
    int i = blockIdx.x * 1024 + t;
    int v = (i < N) ? count[i] + 1 : 0;
    s[t] = v;
    __syncthreads();
    for (int off = 1; off < 1024; off <<= 1) {
        int y = (t >= off) ? s[t - off] : 0;
        __syncthreads();
        s[t] += y;
        __syncthreads();
    }
    if (i < N) row[i + 1] = s[t];
    if (t == 1023) bsum[blockIdx.x] = s[t];
}

// K3b: exclusive scan of block sums (NB <= 128)
__global__ __launch_bounds__(128) void k_scan2(const int* __restrict__ bsum, int NB,
                                               int* __restrict__ boff)
{
    __shared__ int s[128];
    int t = threadIdx.x;
    int v = (t < NB) ? bsum[t] : 0;
    s[t] = v;
    __syncthreads();
    for (int off = 1; off < 128; off <<= 1) {
        int y = (t >= off) ? s[t - off] : 0;
        __syncthreads();
        s[t] += y;
        __syncthreads();
    }
    boff[t] = s[t] - v;
}

// K3c: add block offsets -> row (exclusive CSR offsets, slots include self-loop)
__global__ __launch_bounds__(1024) void k_scan3(int N, int* __restrict__ row,
                                                const int* __restrict__ boff)
{
    int t = threadIdx.x;
    int i = blockIdx.x * 1024 + t;
    if (i == 0) row[0] = 0;
    if (i < N) row[i + 1] += boff[blockIdx.x];
}

// K4: scatter src into CSR order (self-loop slot at segment end stays implicit)
__global__ void k_fill(const int* __restrict__ src, const int* __restrict__ dst, int E,
                       const int* __restrict__ row, int* __restrict__ cursor,
                       int* __restrict__ ssort)
{
    int i = blockIdx.x * 256 + threadIdx.x;
    if (i < E) {
        int d = dst[i];
        int pos = row[d] + atomicAdd(&cursor[d], 1);
        ssort[pos] = src[i];
    }
}

// K5: per-node softmax + aggregation, no max pre-pass (exact: exp(a)/sum(exp(a));
// scores O(10), no fp32 overflow). Wave per node, lane = channel. Unroll-8 = MLP 8.
__global__ __launch_bounds__(256) void k_agg(
    const __hip_bfloat16* __restrict__ xlb,
    const float* __restrict__ s_i, const float* __restrict__ s_j,
    const int* __restrict__ row, const int* __restrict__ ssort,
    const float* __restrict__ bias, int N,
    float* __restrict__ outp, float2* __restrict__ pd,
    float* __restrict__ spread)
{
    int lane = threadIdx.x & 63;
    int wv   = threadIdx.x >> 6;
    int n    = blockIdx.x * 4 + wv;
    if (n >= N) return;
    int r0 = row[n], r1 = row[n + 1];
    int cntE = r1 - r0 - 1;                       // real in-edges (last slot = self)
    float si_n  = s_i[n];
    float eself = __expf(lrelu(si_n + s_j[n], 0.2f));
    float den = eself;
    float acc = eself * __bfloat162float(xlb[(size_t)n * CO + lane]);
    int k = 0;
    int cnt8 = cntE & ~7;
    for (; k < cnt8; k += 8) {
        const int* sp = ssort + r0 + k;
        int sv[8];
#pragma unroll
        for (int u = 0; u < 8; ++u) sv[u] = sp[u];
        float sjv[8];
#pragma unroll
        for (int u = 0; u < 8; ++u) sjv[u] = s_j[sv[u]];
        float xv[8];
#pragma unroll
        for (int u = 0; u < 8; ++u)
            xv[u] = __bfloat162float(xlb[(size_t)sv[u] * CO + lane]);
        float ev[8];
#pragma unroll
        for (int u = 0; u < 8; ++u) ev[u] = __expf(lrelu(si_n + sjv[u], 0.2f));
#pragma unroll
        for (int u = 0; u < 8; ++u) { den += ev[u]; acc = fmaf(ev[u], xv[u], acc); }
    }
    for (; k < cntE; ++k) {
        int s = ssort[r0 + k];
        float e = __expf(lrelu(si_n + s_j[s], 0.2f));
        den += e;
        acc = fmaf(e, __bfloat162float(xlb[(size_t)s * CO + lane]), acc);
    }
    float inv = 1.0f / den;
    float val = acc * inv + bias[lane];
    outp[(size_t)n * CO + lane] = val;
    if (lane == 0) pd[n] = make_float2(si_n, inv);
    int slot = (blockIdx.x * 4 + wv) & 255;
    atomicAdd(&spread[slot * 128 + lane],      val);
    atomicAdd(&spread[slot * 128 + 64 + lane], val * val);
}

// K6: att_weight in ORIGINAL edge order (E real edges then N self-loops).
__global__ void k_att(const int* __restrict__ src, const int* __restrict__ dst, int E, int N,
                      const float2* __restrict__ pd, const float* __restrict__ s_j,
                      float* __restrict__ att)
{
    int i = blockIdx.x * 256 + threadIdx.x;
    int tot = E + N;
    if (i >= tot) return;
    int s, d;
    if (i < E) { s = src[i]; d = dst[i]; } else { s = d = i - E; }
    float2 p = pd[d];
    float a = lrelu(p.x + s_j[s], 0.2f);
    att[i] = __expf(a) * p.y;
}

// K7: reduce BN partials -> per-channel scale/shift
__global__ __launch_bounds__(1024) void k_bnstats(const float* __restrict__ spread, int N,
    const float* __restrict__ gamma, const float* __restrict__ beta,
    float* __restrict__ scale, float* __restrict__ shift)
{
    __shared__ float red[8][128];
    __shared__ float tot[128];
    int c = threadIdx.x & 127;
    int p = threadIdx.x >> 7;
    float a = 0.f;
    for (int s = p; s < 256; s += 8) a += spread[s * 128 + c];
    red[p][c] = a;
    __syncthreads();
    if (threadIdx.x < 128) {
        float t = 0.f;
        for (int q = 0; q < 8; ++q) t += red[q][c];
        tot[c] = t;
    }
    __syncthreads();
    if (threadIdx.x < 64) {
        float inv = 1.f / (float)N;
        float mu  = tot[threadIdx.x] * inv;
        float msq = tot[64 + threadIdx.x] * inv;
        float var = msq - mu * mu;
        float sc  = gamma[threadIdx.x] * rsqrtf(var + 1e-5f);
        scale[threadIdx.x] = sc;
        shift[threadIdx.x] = beta[threadIdx.x] - mu * sc;
    }
}

// K8: in-place BN + leaky(0.01) epilogue, float4-vectorized
__global__ void k_bnapply(float* __restrict__ outp, int N,
                          const float* __restrict__ scale, const float* __restrict__ shift)
{
    int i = blockIdx.x * 256 + threadIdx.x;
    int tot = N * CO / 4;
    if (i >= tot) return;
    float4 v = ((float4*)outp)[i];
    int c0 = (i * 4) & (CO - 1);
    v.x = lrelu(fmaf(scale[c0 + 0], v.x, shift[c0 + 0]), 0.01f);
    v.y = lrelu(fmaf(scale[c0 + 1], v.y, shift[c0 + 1]), 0.01f);
    v.z = lrelu(fmaf(scale[c0 + 2], v.z, shift[c0 + 2]), 0.01f);
    v.w = lrelu(fmaf(scale[c0 + 3], v.w, shift[c0 + 3]), 0.01f);
    ((float4*)outp)[i] = v;
}

extern "C" void kernel_launch(void* const* d_in, const int* in_sizes, int n_in,
                              void* d_out, int out_size, void* d_ws, size_t ws_size,
                              hipStream_t stream)
{
    const float* x    = (const float*)d_in[0];
    const int*   ei   = (const int*)  d_in[1];
    const float* emb  = (const float*)d_in[2];
    const float* W    = (const float*)d_in[3];
    const float* lb   = (const float*)d_in[4];
    const float* ai   = (const float*)d_in[5];
    const float* aj   = (const float*)d_in[6];
    const float* aei  = (const float*)d_in[7];
    const float* aej  = (const float*)d_in[8];
    const float* bias = (const float*)d_in[9];
    const float* gam  = (const float*)d_in[10];
    const float* bet  = (const float*)d_in[11];

    int N = in_sizes[0] / CIN;
    int E = in_sizes[1] / 2;
    const int* srcv = ei;
    const int* dstv = ei + E;

    float* ws = (float*)d_ws;
    size_t o = 0;
    __hip_bfloat16* xlb = (__hip_bfloat16*)(ws + o); o += (size_t)N * CO / 2;
    float* s_i   = ws + o; o += N;
    float* s_j   = ws + o; o += N;
    float* sie   = ws + o; o += N;
    float* sje   = ws + o; o += N;
    float2* pd   = (float2*)(ws + o); o += 2 * (size_t)N;
    int*   row   = (int*)(ws + o); o += (size_t)N + 1;
    o += (o & 1);                                   // even-align
    int*   bsum  = (int*)(ws + o); o += 128;
    int*   boff  = (int*)(ws + o); o += 128;
    size_t zoff  = o;                               // ---- zeroed region start ----
    int*   count = (int*)(ws + o); o += N;
    int*   cursor= (int*)(ws + o); o += N;
    float* spread= ws + o;         o += 256 * 128;
    size_t zbytes = (o - zoff) * sizeof(float);     // ---- zeroed region end ----
    float* scale = ws + o; o += CO;
    float* shift = ws + o; o += CO;
    int*   ssort = (int*)(ws + o); o += E;

    float* out_nodes = (float*)d_out;
    float* out_att   = out_nodes + (size_t)N * CO;

    hipMemsetAsync((void*)count, 0, zbytes, stream);

    k_escore<<<1024, 256, 0, stream>>>(emb, aei, aej, sie, sje, N);
    k_gemm<<<512, 256, 0, stream>>>(x, W, lb, ai, aj, sie, sje, xlb, s_i, s_j, N);
    k_hist<<<(E + 255) / 256, 256, 0, stream>>>(dstv, E, count);
    int NB = (N + 1023) / 1024;
    k_scan1<<<NB, 1024, 0, stream>>>(count, N, row, bsum);
    k_scan2<<<1, 128, 0, stream>>>(bsum, NB, boff);
    k_scan3<<<NB, 1024, 0, stream>>>(N, row, boff);
    k_fill<<<(E + 255) / 256, 256, 0, stream>>>(srcv, dstv, E, row, cursor, ssort);
    k_agg<<<(N + 3) / 4, 256, 0, stream>>>(xlb, s_i, s_j, row, ssort, bias, N,
                                           out_nodes, pd, spread);
    k_att<<<(E + N + 255) / 256, 256, 0, stream>>>(srcv, dstv, E, N, pd, s_j, out_att);
    k_bnstats<<<1, 1024, 0, stream>>>(spread, N, gam, bet, scale, shift);
    k_bnapply<<<((N * CO / 4) + 255) / 256, 256, 0, stream>>>(out_nodes, N, scale, shift);
}

// Round 4
// 553.391 us; speedup vs baseline: 1.7450x; 1.1142x over previous
//
#include <hip/hip_runtime.h>
#include <hip/hip_bf16.h>

#define CIN 128
#define CO  64

typedef __attribute__((ext_vector_type(8))) short shortx8;
typedef __attribute__((ext_vector_type(4))) float floatx4;

__device__ __forceinline__ float lrelu(float x, float s) { return x > 0.f ? x : x * s; }

__device__ __forceinline__ short f2bs(float f) {
    union { __hip_bfloat16 h; short s; } u;
    u.h = __float2bfloat16(f);
    return u.s;
}

__device__ __forceinline__ shortx8 pack8(const float4& a, const float4& b) {
    shortx8 r;
    r[0] = f2bs(a.x); r[1] = f2bs(a.y); r[2] = f2bs(a.z); r[3] = f2bs(a.w);
    r[4] = f2bs(b.x); r[5] = f2bs(b.y); r[6] = f2bs(b.z); r[7] = f2bs(b.w);
    return r;
}

// K0: emb-part of attention scores: sie[n] = emb[n]·att_em_i, sje[n] = emb[n]·att_em_j.
__global__ __launch_bounds__(256) void k_escore(
    const float* __restrict__ emb, const float* __restrict__ aei, const float* __restrict__ aej,
    float* __restrict__ sie, float* __restrict__ sje, int N)
{
    int lane = threadIdx.x & 63;
    int slot = lane & 15, grp = lane >> 4;
    float4 vi = ((const float4*)aei)[slot];
    float4 vj = ((const float4*)aej)[slot];
    int w = blockIdx.x * 4 + (threadIdx.x >> 6);
    int nwaves = gridDim.x * 4;
    int groups = (N + 3) >> 2;
    for (int g = w; g < groups; g += nwaves) {
        int n = g * 4 + grp;
        float pi = 0.f, pj = 0.f;
        if (n < N) {
            float4 e = ((const float4*)(emb + (size_t)n * CO))[slot];
            pi = e.x * vi.x + e.y * vi.y + e.z * vi.z + e.w * vi.w;
            pj = e.x * vj.x + e.y * vj.y + e.z * vj.z + e.w * vj.w;
        }
#pragma unroll
        for (int off = 1; off < 16; off <<= 1) {
            pi += __shfl_xor(pi, off);
            pj += __shfl_xor(pj, off);
        }
        if (slot == 0 && n < N) { sie[n] = pi; sje[n] = pj; }
    }
}

// K1: MFMA GEMM xl = x@W^T + b (16x16x32 bf16), fused score dots + bf16 tile write.
__global__ __launch_bounds__(256) void k_gemm(
    const float* __restrict__ x, const float* __restrict__ W,
    const float* __restrict__ lb, const float* __restrict__ ai, const float* __restrict__ aj,
    const float* __restrict__ sie, const float* __restrict__ sje,
    __hip_bfloat16* __restrict__ xlb, float* __restrict__ s_i, float* __restrict__ s_j, int N)
{
    __shared__ __hip_bfloat16 tile[4][16 * 72];
    const int lane = threadIdx.x & 63;
    const int wv   = threadIdx.x >> 6;
    const int col0 = lane & 15;
    const int quad = lane >> 4;

    shortx8 wf[4][4];
#pragma unroll
    for (int cg = 0; cg < 4; ++cg)
#pragma unroll
        for (int ks = 0; ks < 4; ++ks) {
            const float* wp = W + (cg * 16 + col0) * CIN + ks * 32 + quad * 8;
            float4 w0 = *(const float4*)wp;
            float4 w1 = *(const float4*)(wp + 4);
            wf[cg][ks] = pack8(w0, w1);
        }
    float biasv[4], aiv[4], ajv[4];
#pragma unroll
    for (int cg = 0; cg < 4; ++cg) {
        biasv[cg] = lb[cg * 16 + col0];
        aiv[cg]   = ai[cg * 16 + col0];
        ajv[cg]   = aj[cg * 16 + col0];
    }

    int tiles = (N + 15) >> 4;
    for (int t = blockIdx.x * 4 + wv; t < tiles; t += gridDim.x * 4) {
        int n0 = t * 16;
        int arow = n0 + col0; if (arow > N - 1) arow = N - 1;
        const float* xp = x + (size_t)arow * CIN + quad * 8;
        float4 a0[4], a1[4];
#pragma unroll
        for (int ks = 0; ks < 4; ++ks) {
            a0[ks] = *(const float4*)(xp + ks * 32);
            a1[ks] = *(const float4*)(xp + ks * 32 + 4);
        }
        floatx4 z = {0.f, 0.f, 0.f, 0.f};
        floatx4 acc[4] = {z, z, z, z};
#pragma unroll
        for (int ks = 0; ks < 4; ++ks) {
            shortx8 af = pack8(a0[ks], a1[ks]);
#pragma unroll
            for (int cg = 0; cg < 4; ++cg)
                acc[cg] = __builtin_amdgcn_mfma_f32_16x16x32_bf16(af, wf[cg][ks], acc[cg], 0, 0, 0);
        }
        float pi[4] = {0, 0, 0, 0}, pj[4] = {0, 0, 0, 0};
        __hip_bfloat16* tp = tile[wv];
#pragma unroll
        for (int cg = 0; cg < 4; ++cg)
#pragma unroll
            for (int r = 0; r < 4; ++r) {
                float v = acc[cg][r] + biasv[cg];
                pi[r] = fmaf(v, aiv[cg], pi[r]);
                pj[r] = fmaf(v, ajv[cg], pj[r]);
                tp[(quad * 4 + r) * 72 + cg * 16 + col0] = __float2bfloat16(v);
            }
        __asm__ __volatile__("s_waitcnt lgkmcnt(0)" ::: "memory");
        int rr = lane >> 2, hh = lane & 3;
        int orow = n0 + rr;
        if (orow < N) {
            const float4* sp = (const float4*)(tp + rr * 72 + hh * 16);
            float4 v0 = sp[0], v1 = sp[1];
            float4* gp = (float4*)(xlb + (size_t)orow * CO + hh * 16);
            gp[0] = v0; gp[1] = v1;
        }
#pragma unroll
        for (int r = 0; r < 4; ++r)
#pragma unroll
            for (int off = 1; off < 16; off <<= 1) {
                pi[r] += __shfl_xor(pi[r], off);
                pj[r] += __shfl_xor(pj[r], off);
            }
        if (col0 == 0) {
#pragma unroll
            for (int r = 0; r < 4; ++r) {
                int n = n0 + quad * 4 + r;
                if (n < N) {
                    s_i[n] = sie[n] + pi[r];
                    s_j[n] = sje[n] + pj[r];
                }
            }
        }
    }
}

// K2: in-degree histogram over real edges
__global__ void k_hist(const int* __restrict__ dst, int E, int* __restrict__ count)
{
    int i = blockIdx.x * 256 + threadIdx.x;
    if (i < E) atomicAdd(&count[dst[i]], 1);
}

// K3a: per-block inclusive scan of (count[i]+1)  (+1 = implicit self-loop)
__global__ __launch_bounds__(1024) void k_scan1(const int* __restrict__ count, int N,
                                                int* __restrict__ row, int* __restrict__ bsum)
{
    __shared__ int s[1024];
    int t = threadIdx.x;
    int i = blockIdx.x * 1024 + t;
    int v = (i < N) ? count[i] + 1 : 0;
    s[t] = v;
    __syncthreads();
    for (int off = 1; off < 1024; off <<= 1) {
        int y = (t >= off) ? s[t - off] : 0;
        __syncthreads();
        s[t] += y;
        __syncthreads();
    }
    if (i < N) row[i + 1] = s[t];
    if (t == 1023) bsum[blockIdx.x] = s[t];
}

// K3b: exclusive scan of block sums (NB <= 128)
__global__ __launch_bounds__(128) void k_scan2(const int* __restrict__ bsum, int NB,
                                               int* __restrict__ boff)
{
    __shared__ int s[128];
    int t = threadIdx.x;
    int v = (t < NB) ? bsum[t] : 0;
    s[t] = v;
    __syncthreads();
    for (int off = 1; off < 128; off <<= 1) {
        int y = (t >= off) ? s[t - off] : 0;
        __syncthreads();
        s[t] += y;
        __syncthreads();
    }
    boff[t] = s[t] - v;
}

// K3c: add block offsets -> row (exclusive CSR offsets, slots include self-loop)
__global__ __launch_bounds__(1024) void k_scan3(int N, int* __restrict__ row,
                                                const int* __restrict__ boff)
{
    int t = threadIdx.x;
    int i = blockIdx.x * 1024 + t;
    if (i == 0) row[0] = 0;
    if (i < N) row[i + 1] += boff[blockIdx.x];
}

// K4a: bucket-partition edges (bucket = dst>>7, 128 nodes). Per-block LDS histogram,
// one global atomicAdd per non-empty bucket reserves a contiguous run in ebuf, then
// re-read edges and scatter packed (src | doff<<17) u32 into the run. All of a run's
// writes come from ONE block -> one XCD's L2 -> lines merge before writeback (fixes
// the 16x write amplification of the old global-cursor scatter).
#define BIN_CHUNK 8192
__global__ __launch_bounds__(256) void k_binA(
    const int* __restrict__ src, const int* __restrict__ dst, int E, int N,
    const int* __restrict__ row, int* __restrict__ gcur, unsigned* __restrict__ ebuf)
{
    __shared__ unsigned hist[1024];
    __shared__ unsigned gstart[1024];
    int base = blockIdx.x * BIN_CHUNK;
    int cnt  = min(BIN_CHUNK, E - base);
    for (int b = threadIdx.x; b < 1024; b += 256) hist[b] = 0;
    __syncthreads();
    for (int k = threadIdx.x; k < cnt; k += 256) {
        int d = dst[base + k];
        atomicAdd(&hist[d >> 7], 1u);
    }
    __syncthreads();
    for (int b = threadIdx.x; b < 1024; b += 256) {
        unsigned c = hist[b];
        if (c) {
            int nb = b << 7;                              // bucket's first node
            int ebase = row[nb] - nb;                     // edges before bucket (excl self slots)
            gstart[b] = (unsigned)ebase + (unsigned)atomicAdd(&gcur[b], (int)c);
        }
        hist[b] = 0;                                      // reuse as local cursor
    }
    __syncthreads();
    for (int k = threadIdx.x; k < cnt; k += 256) {
        int s = src[base + k];
        int d = dst[base + k];
        int b = d >> 7;
        unsigned packed = (unsigned)s | ((unsigned)(d & 127) << 17);
        unsigned pos = gstart[b] + atomicAdd(&hist[b], 1u);
        ebuf[pos] = packed;
    }
}

// K4b: one block per bucket: counting-sort bucket's edges into ssort CSR segments.
// All writes land in the bucket's contiguous ~17KB region from one block -> merged.
__global__ __launch_bounds__(256) void k_binB(
    const int* __restrict__ row, const unsigned* __restrict__ ebuf,
    int* __restrict__ ssort, int N)
{
    __shared__ int lrow[129];
    __shared__ int lcur[128];
    int b = blockIdx.x;
    int start = b << 7;
    int sz = min(128, N - start);
    for (int i = threadIdx.x; i <= sz; i += 256) lrow[i] = row[start + i];
    for (int i = threadIdx.x; i < 128; i += 256) lcur[i] = 0;
    __syncthreads();
    int ebase = lrow[0] - start;
    int cntB  = (lrow[sz] - (start + sz)) - ebase;
    for (int k = threadIdx.x; k < cntB; k += 256) {
        unsigned e = ebuf[ebase + k];
        int s    = (int)(e & 0x1FFFFu);
        int doff = (int)(e >> 17);
        int p = atomicAdd(&lcur[doff], 1);
        ssort[lrow[doff] + p] = s;
    }
}

// K5: per-node softmax + aggregation, no max pre-pass. Wave per node, lane = channel.
__global__ __launch_bounds__(256) void k_agg(
    const __hip_bfloat16* __restrict__ xlb,
    const float* __restrict__ s_i, const float* __restrict__ s_j,
    const int* __restrict__ row, const int* __restrict__ ssort,
    const float* __restrict__ bias, int N,
    float* __restrict__ outp, float2* __restrict__ pd,
    float* __restrict__ spread)
{
    int lane = threadIdx.x & 63;
    int wv   = threadIdx.x >> 6;
    int n    = blockIdx.x * 4 + wv;
    if (n >= N) return;
    int r0 = row[n], r1 = row[n + 1];
    int cntE = r1 - r0 - 1;
    float si_n  = s_i[n];
    float eself = __expf(lrelu(si_n + s_j[n], 0.2f));
    float den = eself;
    float acc = eself * __bfloat162float(xlb[(size_t)n * CO + lane]);
    int k = 0;
    int cnt8 = cntE & ~7;
    for (; k < cnt8; k += 8) {
        const int* sp = ssort + r0 + k;
        int sv[8];
#pragma unroll
        for (int u = 0; u < 8; ++u) sv[u] = sp[u];
        float sjv[8];
#pragma unroll
        for (int u = 0; u < 8; ++u) sjv[u] = s_j[sv[u]];
        float xv[8];
#pragma unroll
        for (int u = 0; u < 8; ++u)
            xv[u] = __bfloat162float(xlb[(size_t)sv[u] * CO + lane]);
        float ev[8];
#pragma unroll
        for (int u = 0; u < 8; ++u) ev[u] = __expf(lrelu(si_n + sjv[u], 0.2f));
#pragma unroll
        for (int u = 0; u < 8; ++u) { den += ev[u]; acc = fmaf(ev[u], xv[u], acc); }
    }
    for (; k < cntE; ++k) {
        int s = ssort[r0 + k];
        float e = __expf(lrelu(si_n + s_j[s], 0.2f));
        den += e;
        acc = fmaf(e, __bfloat162float(xlb[(size_t)s * CO + lane]), acc);
    }
    float inv = 1.0f / den;
    float val = acc * inv + bias[lane];
    outp[(size_t)n * CO + lane] = val;
    if (lane == 0) pd[n] = make_float2(si_n, inv);
    int slot = (blockIdx.x * 4 + wv) & 255;
    atomicAdd(&spread[slot * 128 + lane],      val);
    atomicAdd(&spread[slot * 128 + 64 + lane], val * val);
}

// K6: att_weight in ORIGINAL edge order (E real edges then N self-loops).
__global__ void k_att(const int* __restrict__ src, const int* __restrict__ dst, int E, int N,
                      const float2* __restrict__ pd, const float* __restrict__ s_j,
                      float* __restrict__ att)
{
    int i = blockIdx.x * 256 + threadIdx.x;
    int tot = E + N;
    if (i >= tot) return;
    int s, d;
    if (i < E) { s = src[i]; d = dst[i]; } else { s = d = i - E; }
    float2 p = pd[d];
    float a = lrelu(p.x + s_j[s], 0.2f);
    att[i] = __expf(a) * p.y;
}

// K7: reduce BN partials -> per-channel scale/shift
__global__ __launch_bounds__(1024) void k_bnstats(const float* __restrict__ spread, int N,
    const float* __restrict__ gamma, const float* __restrict__ beta,
    float* __restrict__ scale, float* __restrict__ shift)
{
    __shared__ float red[8][128];
    __shared__ float tot[128];
    int c = threadIdx.x & 127;
    int p = threadIdx.x >> 7;
    float a = 0.f;
    for (int s = p; s < 256; s += 8) a += spread[s * 128 + c];
    red[p][c] = a;
    __syncthreads();
    if (threadIdx.x < 128) {
        float t = 0.f;
        for (int q = 0; q < 8; ++q) t += red[q][c];
        tot[c] = t;
    }
    __syncthreads();
    if (threadIdx.x < 64) {
        float inv = 1.f / (float)N;
        float mu  = tot[threadIdx.x] * inv;
        float msq = tot[64 + threadIdx.x] * inv;
        float var = msq - mu * mu;
        float sc  = gamma[threadIdx.x] * rsqrtf(var + 1e-5f);
        scale[threadIdx.x] = sc;
        shift[threadIdx.x] = beta[threadIdx.x] - mu * sc;
    }
}

// K8: in-place BN + leaky(0.01) epilogue, float4-vectorized
__global__ void k_bnapply(float* __restrict__ outp, int N,
                          const float* __restrict__ scale, const float* __restrict__ shift)
{
    int i = blockIdx.x * 256 + threadIdx.x;
    int tot = N * CO / 4;
    if (i >= tot) return;
    float4 v = ((float4*)outp)[i];
    int c0 = (i * 4) & (CO - 1);
    v.x = lrelu(fmaf(scale[c0 + 0], v.x, shift[c0 + 0]), 0.01f);
    v.y = lrelu(fmaf(scale[c0 + 1], v.y, shift[c0 + 1]), 0.01f);
    v.z = lrelu(fmaf(scale[c0 + 2], v.z, shift[c0 + 2]), 0.01f);
    v.w = lrelu(fmaf(scale[c0 + 3], v.w, shift[c0 + 3]), 0.01f);
    ((float4*)outp)[i] = v;
}

extern "C" void kernel_launch(void* const* d_in, const int* in_sizes, int n_in,
                              void* d_out, int out_size, void* d_ws, size_t ws_size,
                              hipStream_t stream)
{
    const float* x    = (const float*)d_in[0];
    const int*   ei   = (const int*)  d_in[1];
    const float* emb  = (const float*)d_in[2];
    const float* W    = (const float*)d_in[3];
    const float* lb   = (const float*)d_in[4];
    const float* ai   = (const float*)d_in[5];
    const float* aj   = (const float*)d_in[6];
    const float* aei  = (const float*)d_in[7];
    const float* aej  = (const float*)d_in[8];
    const float* bias = (const float*)d_in[9];
    const float* gam  = (const float*)d_in[10];
    const float* bet  = (const float*)d_in[11];

    int N = in_sizes[0] / CIN;
    int E = in_sizes[1] / 2;
    const int* srcv = ei;
    const int* dstv = ei + E;
    int NBUK = (N + 127) >> 7;

    float* ws = (float*)d_ws;
    size_t o = 0;
    __hip_bfloat16* xlb = (__hip_bfloat16*)(ws + o); o += (size_t)N * CO / 2;
    float* s_i   = ws + o; o += N;
    float* s_j   = ws + o; o += N;
    float* sie   = ws + o; o += N;
    float* sje   = ws + o; o += N;
    float2* pd   = (float2*)(ws + o); o += 2 * (size_t)N;
    int*   row   = (int*)(ws + o); o += (size_t)N + 1;
    o += (o & 1);                                   // even-align
    int*   bsum  = (int*)(ws + o); o += 128;
    int*   boff  = (int*)(ws + o); o += 128;
    size_t zoff  = o;                               // ---- zeroed region start ----
    int*   count = (int*)(ws + o); o += N;
    int*   gcur  = (int*)(ws + o); o += 1024;
    float* spread= ws + o;         o += 256 * 128;
    size_t zbytes = (o - zoff) * sizeof(float);     // ---- zeroed region end ----
    float* scale = ws + o; o += CO;
    float* shift = ws + o; o += CO;
    unsigned* ebuf = (unsigned*)(ws + o); o += E;
    int*   ssort = (int*)(ws + o); o += E;

    float* out_nodes = (float*)d_out;
    float* out_att   = out_nodes + (size_t)N * CO;

    hipMemsetAsync((void*)count, 0, zbytes, stream);

    k_escore<<<1024, 256, 0, stream>>>(emb, aei, aej, sie, sje, N);
    k_gemm<<<512, 256, 0, stream>>>(x, W, lb, ai, aj, sie, sje, xlb, s_i, s_j, N);
    k_hist<<<(E + 255) / 256, 256, 0, stream>>>(dstv, E, count);
    int NB = (N + 1023) / 1024;
    k_scan1<<<NB, 1024, 0, stream>>>(count, N, row, bsum);
    k_scan2<<<1, 128, 0, stream>>>(bsum, NB, boff);
    k_scan3<<<NB, 1024, 0, stream>>>(N, row, boff);
    k_binA<<<(E + BIN_CHUNK - 1) / BIN_CHUNK, 256, 0, stream>>>(srcv, dstv, E, N, row, gcur, ebuf);
    k_binB<<<NBUK, 256, 0, stream>>>(row, ebuf, ssort, N);
    k_agg<<<(N + 3) / 4, 256, 0, stream>>>(xlb, s_i, s_j, row, ssort, bias, N,
                                           out_nodes, pd, spread);
    k_att<<<(E + N + 255) / 256, 256, 0, stream>>>(srcv, dstv, E, N, pd, s_j, out_att);
    k_bnstats<<<1, 1024, 0, stream>>>(spread, N, gam, bet, scale, shift);
    k_bnapply<<<((N * CO / 4) + 255) / 256, 256, 0, stream>>>(out_nodes, N, scale, shift);
}

// Round 5
// 450.706 us; speedup vs baseline: 2.1426x; 1.2278x over previous
//
#include <hip/hip_runtime.h>
#include <hip/hip_bf16.h>

#define CIN 128
#define CO  64

typedef __attribute__((ext_vector_type(8))) short shortx8;
typedef __attribute__((ext_vector_type(4))) float floatx4;

__device__ __forceinline__ float lrelu(float x, float s) { return x > 0.f ? x : x * s; }

__device__ __forceinline__ short f2bs(float f) {
    union { __hip_bfloat16 h; short s; } u;
    u.h = __float2bfloat16(f);
    return u.s;
}

__device__ __forceinline__ shortx8 pack8(const float4& a, const float4& b) {
    shortx8 r;
    r[0] = f2bs(a.x); r[1] = f2bs(a.y); r[2] = f2bs(a.z); r[3] = f2bs(a.w);
    r[4] = f2bs(b.x); r[5] = f2bs(b.y); r[6] = f2bs(b.z); r[7] = f2bs(b.w);
    return r;
}

// K0: emb-part of attention scores: sie[n] = emb[n]·att_em_i, sje[n] = emb[n]·att_em_j.
__global__ __launch_bounds__(256) void k_escore(
    const float* __restrict__ emb, const float* __restrict__ aei, const float* __restrict__ aej,
    float* __restrict__ sie, float* __restrict__ sje, int N)
{
    int lane = threadIdx.x & 63;
    int slot = lane & 15, grp = lane >> 4;
    float4 vi = ((const float4*)aei)[slot];
    float4 vj = ((const float4*)aej)[slot];
    int w = blockIdx.x * 4 + (threadIdx.x >> 6);
    int nwaves = gridDim.x * 4;
    int groups = (N + 3) >> 2;
    for (int g = w; g < groups; g += nwaves) {
        int n = g * 4 + grp;
        float pi = 0.f, pj = 0.f;
        if (n < N) {
            float4 e = ((const float4*)(emb + (size_t)n * CO))[slot];
            pi = e.x * vi.x + e.y * vi.y + e.z * vi.z + e.w * vi.w;
            pj = e.x * vj.x + e.y * vj.y + e.z * vj.z + e.w * vj.w;
        }
#pragma unroll
        for (int off = 1; off < 16; off <<= 1) {
            pi += __shfl_xor(pi, off);
            pj += __shfl_xor(pj, off);
        }
        if (slot == 0 && n < N) { sie[n] = pi; sje[n] = pj; }
    }
}

// K1: MFMA GEMM xl = x@W^T + b (16x16x32 bf16), fused score dots + bf16 tile write.
__global__ __launch_bounds__(256) void k_gemm(
    const float* __restrict__ x, const float* __restrict__ W,
    const float* __restrict__ lb, const float* __restrict__ ai, const float* __restrict__ aj,
    const float* __restrict__ sie, const float* __restrict__ sje,
    __hip_bfloat16* __restrict__ xlb, float* __restrict__ s_i, float* __restrict__ s_j, int N)
{
    __shared__ __hip_bfloat16 tile[4][16 * 72];
    const int lane = threadIdx.x & 63;
    const int wv   = threadIdx.x >> 6;
    const int col0 = lane & 15;
    const int quad = lane >> 4;

    shortx8 wf[4][4];
#pragma unroll
    for (int cg = 0; cg < 4; ++cg)
#pragma unroll
        for (int ks = 0; ks < 4; ++ks) {
            const float* wp = W + (cg * 16 + col0) * CIN + ks * 32 + quad * 8;
            float4 w0 = *(const float4*)wp;
            float4 w1 = *(const float4*)(wp + 4);
            wf[cg][ks] = pack8(w0, w1);
        }
    float biasv[4], aiv[4], ajv[4];
#pragma unroll
    for (int cg = 0; cg < 4; ++cg) {
        biasv[cg] = lb[cg * 16 + col0];
        aiv[cg]   = ai[cg * 16 + col0];
        ajv[cg]   = aj[cg * 16 + col0];
    }

    int tiles = (N + 15) >> 4;
    for (int t = blockIdx.x * 4 + wv; t < tiles; t += gridDim.x * 4) {
        int n0 = t * 16;
        int arow = n0 + col0; if (arow > N - 1) arow = N - 1;
        const float* xp = x + (size_t)arow * CIN + quad * 8;
        float4 a0[4], a1[4];
#pragma unroll
        for (int ks = 0; ks < 4; ++ks) {
            a0[ks] = *(const float4*)(xp + ks * 32);
            a1[ks] = *(const float4*)(xp + ks * 32 + 4);
        }
        floatx4 z = {0.f, 0.f, 0.f, 0.f};
        floatx4 acc[4] = {z, z, z, z};
#pragma unroll
        for (int ks = 0; ks < 4; ++ks) {
            shortx8 af = pack8(a0[ks], a1[ks]);
#pragma unroll
            for (int cg = 0; cg < 4; ++cg)
                acc[cg] = __builtin_amdgcn_mfma_f32_16x16x32_bf16(af, wf[cg][ks], acc[cg], 0, 0, 0);
        }
        float pi[4] = {0, 0, 0, 0}, pj[4] = {0, 0, 0, 0};
        __hip_bfloat16* tp = tile[wv];
#pragma unroll
        for (int cg = 0; cg < 4; ++cg)
#pragma unroll
            for (int r = 0; r < 4; ++r) {
                float v = acc[cg][r] + biasv[cg];
                pi[r] = fmaf(v, aiv[cg], pi[r]);
                pj[r] = fmaf(v, ajv[cg], pj[r]);
                tp[(quad * 4 + r) * 72 + cg * 16 + col0] = __float2bfloat16(v);
            }
        __asm__ __volatile__("s_waitcnt lgkmcnt(0)" ::: "memory");
        int rr = lane >> 2, hh = lane & 3;
        int orow = n0 + rr;
        if (orow < N) {
            const float4* sp = (const float4*)(tp + rr * 72 + hh * 16);
            float4 v0 = sp[0], v1 = sp[1];
            float4* gp = (float4*)(xlb + (size_t)orow * CO + hh * 16);
            gp[0] = v0; gp[1] = v1;
        }
#pragma unroll
        for (int r = 0; r < 4; ++r)
#pragma unroll
            for (int off = 1; off < 16; off <<= 1) {
                pi[r] += __shfl_xor(pi[r], off);
                pj[r] += __shfl_xor(pj[r], off);
            }
        if (col0 == 0) {
#pragma unroll
            for (int r = 0; r < 4; ++r) {
                int n = n0 + quad * 4 + r;
                if (n < N) {
                    s_i[n] = sie[n] + pi[r];
                    s_j[n] = sje[n] + pj[r];
                }
            }
        }
    }
}

#define BIN_CHUNK 8192
// K2a: bucket histogram (bucket = dst>>7). LDS hist per chunk, ONE global atomic per
// (block,bucket) on a 4KB array — replaces 3.2M scattered per-node atomics (the old
// k_hist's 100MB memory-side write traffic).
__global__ __launch_bounds__(256) void k_bhist(const int* __restrict__ dst, int E,
                                               int* __restrict__ bcnt)
{
    __shared__ int h[1024];
    int base = blockIdx.x * BIN_CHUNK;
    int cnt  = min(BIN_CHUNK, E - base);
    for (int i = threadIdx.x; i < 1024; i += 256) h[i] = 0;
    __syncthreads();
    for (int k = threadIdx.x; k < cnt; k += 256) atomicAdd(&h[dst[base + k] >> 7], 1);
    __syncthreads();
    for (int i = threadIdx.x; i < 1024; i += 256)
        if (h[i]) atomicAdd(&bcnt[i], h[i]);
}

// K2b: single-block exclusive scan of 1024 bucket counts -> bucket edge bases
__global__ __launch_bounds__(1024) void k_bscan(const int* __restrict__ bcnt,
                                                int* __restrict__ bbase)
{
    __shared__ int s[1024];
    int t = threadIdx.x;
    int v = bcnt[t];
    s[t] = v;
    __syncthreads();
    for (int off = 1; off < 1024; off <<= 1) {
        int y = (t >= off) ? s[t - off] : 0;
        __syncthreads();
        s[t] += y;
        __syncthreads();
    }
    bbase[t] = s[t] - v;                          // exclusive
}

// K3a: bucket-partition edges. Per-block LDS histogram, one global atomicAdd per
// non-empty bucket reserves a contiguous run in ebuf, then re-read and scatter packed
// (src | doff<<17). Runs are block-local -> lines merge in one XCD's L2.
__global__ __launch_bounds__(256) void k_binA(
    const int* __restrict__ src, const int* __restrict__ dst, int E,
    const int* __restrict__ bbase, int* __restrict__ gcur, unsigned* __restrict__ ebuf)
{
    __shared__ unsigned hist[1024];
    __shared__ unsigned gstart[1024];
    int base = blockIdx.x * BIN_CHUNK;
    int cnt  = min(BIN_CHUNK, E - base);
    for (int b = threadIdx.x; b < 1024; b += 256) hist[b] = 0;
    __syncthreads();
    for (int k = threadIdx.x; k < cnt; k += 256) {
        int d = dst[base + k];
        atomicAdd(&hist[d >> 7], 1u);
    }
    __syncthreads();
    for (int b = threadIdx.x; b < 1024; b += 256) {
        unsigned c = hist[b];
        if (c) gstart[b] = (unsigned)bbase[b] + (unsigned)atomicAdd(&gcur[b], (int)c);
        hist[b] = 0;                              // reuse as local cursor
    }
    __syncthreads();
    for (int k = threadIdx.x; k < cnt; k += 256) {
        int s = src[base + k];
        int d = dst[base + k];
        int b = d >> 7;
        unsigned packed = (unsigned)s | ((unsigned)(d & 127) << 17);
        unsigned pos = gstart[b] + atomicAdd(&hist[b], 1u);
        ebuf[pos] = packed;
    }
}

// K3b: one block per bucket. From the bucket's packed edges: LDS-histogram the 128
// node degrees, LDS-scan -> write CSR row directly (row[n] = edges_before + n, self
// slot at segment end), then counting-sort srcs into ssort. No per-node global atomics.
__global__ __launch_bounds__(256) void k_binB(
    const int* __restrict__ bbase, const unsigned* __restrict__ ebuf,
    int* __restrict__ row, int* __restrict__ ssort, int N, int E, int NBUK)
{
    __shared__ int h[128];
    __shared__ int sc[128];
    __shared__ int lrow[128];
    __shared__ int lcur[128];
    int b = blockIdx.x;
    int start = b << 7;
    int sz = min(128, N - start);
    int eb   = bbase[b];
    int cntB = bbase[b + 1] - eb;                 // b+1 <= 1023 always (NBUK <= 782)
    int t = threadIdx.x;
    if (t < 128) { h[t] = 0; lcur[t] = 0; }
    __syncthreads();
    for (int k = t; k < cntB; k += 256) atomicAdd(&h[ebuf[eb + k] >> 17], 1);
    __syncthreads();
    if (t < 128) sc[t] = h[t];
    __syncthreads();
    for (int off = 1; off < 128; off <<= 1) {
        int y = (t >= off && t < 128) ? sc[t - off] : 0;
        __syncthreads();
        if (t < 128) sc[t] += y;
        __syncthreads();
    }
    if (t < sz) {
        int r = eb + (sc[t] - h[t]) + start + t;  // edges_before + self_slots_before
        lrow[t] = r;
        row[start + t] = r;
    }
    if (b == NBUK - 1 && t == 0) row[N] = E + N;
    __syncthreads();
    for (int k = t; k < cntB; k += 256) {
        unsigned e = ebuf[eb + k];
        int doff = (int)(e >> 17);
        int s    = (int)(e & 0x1FFFFu);
        int p = atomicAdd(&lcur[doff], 1);
        ssort[lrow[doff] + p] = s;
    }
}

// K5: per-node softmax + aggregation, no max pre-pass. Wave per node, lane = channel.
__global__ __launch_bounds__(256) void k_agg(
    const __hip_bfloat16* __restrict__ xlb,
    const float* __restrict__ s_i, const float* __restrict__ s_j,
    const int* __restrict__ row, const int* __restrict__ ssort,
    const float* __restrict__ bias, int N,
    float* __restrict__ outp, float2* __restrict__ pd,
    float* __restrict__ spread)
{
    int lane = threadIdx.x & 63;
    int wv   = threadIdx.x >> 6;
    int n    = blockIdx.x * 4 + wv;
    if (n >= N) return;
    int r0 = row[n], r1 = row[n + 1];
    int cntE = r1 - r0 - 1;
    float si_n  = s_i[n];
    float eself = __expf(lrelu(si_n + s_j[n], 0.2f));
    float den = eself;
    float acc = eself * __bfloat162float(xlb[(size_t)n * CO + lane]);
    int k = 0;
    int cnt8 = cntE & ~7;
    for (; k < cnt8; k += 8) {
        const int* sp = ssort + r0 + k;
        int sv[8];
#pragma unroll
        for (int u = 0; u < 8; ++u) sv[u] = sp[u];
        float sjv[8];
#pragma unroll
        for (int u = 0; u < 8; ++u) sjv[u] = s_j[sv[u]];
        float xv[8];
#pragma unroll
        for (int u = 0; u < 8; ++u)
            xv[u] = __bfloat162float(xlb[(size_t)sv[u] * CO + lane]);
        float ev[8];
#pragma unroll
        for (int u = 0; u < 8; ++u) ev[u] = __expf(lrelu(si_n + sjv[u], 0.2f));
#pragma unroll
        for (int u = 0; u < 8; ++u) { den += ev[u]; acc = fmaf(ev[u], xv[u], acc); }
    }
    for (; k < cntE; ++k) {
        int s = ssort[r0 + k];
        float e = __expf(lrelu(si_n + s_j[s], 0.2f));
        den += e;
        acc = fmaf(e, __bfloat162float(xlb[(size_t)s * CO + lane]), acc);
    }
    float inv = 1.0f / den;
    float val = acc * inv + bias[lane];
    outp[(size_t)n * CO + lane] = val;
    if (lane == 0) pd[n] = make_float2(si_n, inv);
    int slot = (blockIdx.x * 4 + wv) & 255;
    atomicAdd(&spread[slot * 128 + lane],      val);
    atomicAdd(&spread[slot * 128 + 64 + lane], val * val);
}

// K6: att_weight in ORIGINAL edge order (E real edges then N self-loops).
__global__ void k_att(const int* __restrict__ src, const int* __restrict__ dst, int E, int N,
                      const float2* __restrict__ pd, const float* __restrict__ s_j,
                      float* __restrict__ att)
{
    int i = blockIdx.x * 256 + threadIdx.x;
    int tot = E + N;
    if (i >= tot) return;
    int s, d;
    if (i < E) { s = src[i]; d = dst[i]; } else { s = d = i - E; }
    float2 p = pd[d];
    float a = lrelu(p.x + s_j[s], 0.2f);
    att[i] = __expf(a) * p.y;
}

// K7: reduce BN partials -> per-channel scale/shift
__global__ __launch_bounds__(1024) void k_bnstats(const float* __restrict__ spread, int N,
    const float* __restrict__ gamma, const float* __restrict__ beta,
    float* __restrict__ scale, float* __restrict__ shift)
{
    __shared__ float red[8][128];
    __shared__ float tot[128];
    int c = threadIdx.x & 127;
    int p = threadIdx.x >> 7;
    float a = 0.f;
    for (int s = p; s < 256; s += 8) a += spread[s * 128 + c];
    red[p][c] = a;
    __syncthreads();
    if (threadIdx.x < 128) {
        float t = 0.f;
        for (int q = 0; q < 8; ++q) t += red[q][c];
        tot[c] = t;
    }
    __syncthreads();
    if (threadIdx.x < 64) {
        float inv = 1.f / (float)N;
        float mu  = tot[threadIdx.x] * inv;
        float msq = tot[64 + threadIdx.x] * inv;
        float var = msq - mu * mu;
        float sc  = gamma[threadIdx.x] * rsqrtf(var + 1e-5f);
        scale[threadIdx.x] = sc;
        shift[threadIdx.x] = beta[threadIdx.x] - mu * sc;
    }
}

// K8: in-place BN + leaky(0.01) epilogue, float4-vectorized
__global__ void k_bnapply(float* __restrict__ outp, int N,
                          const float* __restrict__ scale, const float* __restrict__ shift)
{
    int i = blockIdx.x * 256 + threadIdx.x;
    int tot = N * CO / 4;
    if (i >= tot) return;
    float4 v = ((float4*)outp)[i];
    int c0 = (i * 4) & (CO - 1);
    v.x = lrelu(fmaf(scale[c0 + 0], v.x, shift[c0 + 0]), 0.01f);
    v.y = lrelu(fmaf(scale[c0 + 1], v.y, shift[c0 + 1]), 0.01f);
    v.z = lrelu(fmaf(scale[c0 + 2], v.z, shift[c0 + 2]), 0.01f);
    v.w = lrelu(fmaf(scale[c0 + 3], v.w, shift[c0 + 3]), 0.01f);
    ((float4*)outp)[i] = v;
}

extern "C" void kernel_launch(void* const* d_in, const int* in_sizes, int n_in,
                              void* d_out, int out_size, void* d_ws, size_t ws_size,
                              hipStream_t stream)
{
    const float* x    = (const float*)d_in[0];
    const int*   ei   = (const int*)  d_in[1];
    const float* emb  = (const float*)d_in[2];
    const float* W    = (const float*)d_in[3];
    const float* lb   = (const float*)d_in[4];
    const float* ai   = (const float*)d_in[5];
    const float* aj   = (const float*)d_in[6];
    const float* aei  = (const float*)d_in[7];
    const float* aej  = (const float*)d_in[8];
    const float* bias = (const float*)d_in[9];
    const float* gam  = (const float*)d_in[10];
    const float* bet  = (const float*)d_in[11];

    int N = in_sizes[0] / CIN;
    int E = in_sizes[1] / 2;
    const int* srcv = ei;
    const int* dstv = ei + E;
    int NBUK = (N + 127) >> 7;

    float* ws = (float*)d_ws;
    size_t o = 0;
    __hip_bfloat16* xlb = (__hip_bfloat16*)(ws + o); o += (size_t)N * CO / 2;
    float* s_i   = ws + o; o += N;
    float* s_j   = ws + o; o += N;
    float* sie   = ws + o; o += N;
    float* sje   = ws + o; o += N;
    float2* pd   = (float2*)(ws + o); o += 2 * (size_t)N;
    int*   row   = (int*)(ws + o); o += (size_t)N + 1;
    o += (o & 1);                                   // even-align
    int*   bbase = (int*)(ws + o); o += 1024;
    size_t zoff  = o;                               // ---- zeroed region start ----
    int*   bcnt  = (int*)(ws + o); o += 1024;
    int*   gcur  = (int*)(ws + o); o += 1024;
    float* spread= ws + o;         o += 256 * 128;
    size_t zbytes = (o - zoff) * sizeof(float);     // ---- zeroed region end ----
    float* scale = ws + o; o += CO;
    float* shift = ws + o; o += CO;
    unsigned* ebuf = (unsigned*)(ws + o); o += E;
    int*   ssort = (int*)(ws + o); o += E;

    float* out_nodes = (float*)d_out;
    float* out_att   = out_nodes + (size_t)N * CO;

    hipMemsetAsync((void*)bcnt, 0, zbytes, stream);

    int CHB = (E + BIN_CHUNK - 1) / BIN_CHUNK;
    k_escore<<<1024, 256, 0, stream>>>(emb, aei, aej, sie, sje, N);
    k_gemm<<<512, 256, 0, stream>>>(x, W, lb, ai, aj, sie, sje, xlb, s_i, s_j, N);
    k_bhist<<<CHB, 256, 0, stream>>>(dstv, E, bcnt);
    k_bscan<<<1, 1024, 0, stream>>>(bcnt, bbase);
    k_binA<<<CHB, 256, 0, stream>>>(srcv, dstv, E, bbase, gcur, ebuf);
    k_binB<<<NBUK, 256, 0, stream>>>(bbase, ebuf, row, ssort, N, E, NBUK);
    k_agg<<<(N + 3) / 4, 256, 0, stream>>>(xlb, s_i, s_j, row, ssort, bias, N,
                                           out_nodes, pd, spread);
    k_att<<<(E + N + 255) / 256, 256, 0, stream>>>(srcv, dstv, E, N, pd, s_j, out_att);
    k_bnstats<<<1, 1024, 0, stream>>>(spread, N, gam, bet, scale, shift);
    k_bnapply<<<((N * CO / 4) + 255) / 256, 256, 0, stream>>>(out_nodes, N, scale, shift);
}